// Round 13
// baseline (77.569 us; speedup 1.0000x reference)
//
#include <hip/hip_runtime.h>
#include <math.h>

#define EPS_BN 1e-5f

typedef float  f32x4  __attribute__((ext_vector_type(4)));
typedef float  f32x2  __attribute__((ext_vector_type(2)));
typedef short  bf16x8 __attribute__((ext_vector_type(8)));

__device__ inline unsigned short f2bf(float f) {
    union { float f; unsigned u; } c; c.f = f;
    unsigned u = c.u;
    return (unsigned short)((u + 0x7FFFu + ((u >> 16) & 1u)) >> 16);  // RNE
}
// v_cvt_pk_bf16_f32: lo=cvt(a), hi=cvt(b), RNE — bit-identical to f2bf pair
__device__ inline unsigned cvtpk_bf16(float a, float b) {
    unsigned r;
    asm("v_cvt_pk_bf16_f32 %0, %1, %2" : "=v"(r) : "v"(a), "v"(b));
    return r;
}

// ---------------------------------------------------------------------------
// Kernel 1: conv1(pk_fma) + conv2(MFMA, B-frag gathered from global) +
//   bf16 flat + exact4 — 2 img/block; blocks 0..199 also pack fc1_w -> Bp.
// ---------------------------------------------------------------------------
__global__ __launch_bounds__(256, 8) void k_conv(
    const float* __restrict__ x,
    const float* __restrict__ c1w, const float* __restrict__ c1b,
    const float* __restrict__ c2w, const float* __restrict__ c2b,
    const float* __restrict__ fc1w, unsigned short* __restrict__ Bp,
    unsigned short* __restrict__ flatb, float* __restrict__ exact4g, int bsz)
{
    __shared__ float sx[2][900];                          // 30x30 halo input; later flat(bf16)
    __shared__ __align__(16) unsigned short s1t[2][16][16][8]; // bf16 conv1 out, halo
    __shared__ float s1f[2][4][12][8];                    // f32 corner for exact heads
    __shared__ unsigned short lut16[56];                  // qa -> elem offset in s1t

    const int tid  = threadIdx.x;
    const int img0 = blockIdx.x * 2;

    // ---- blocks 0..199 pack Bp (fc1 weights)
    if (blockIdx.x < 200) {
        int t = blockIdx.x * 256 + tid;        // < 51200
        int j  = t & 7;
        int l  = (t >> 3) & 63;
        int nf = (t >> 9) & 3;
        int kb = t >> 11;
        int k  = kb * 32 + (l >> 4) * 8 + j;
        int o  = nf * 16 + (l & 15);
        float v = (k < 784) ? fc1w[o * 784 + k] : 0.f;
        Bp[t] = f2bf(v);
    }

    // ---- conv2 address LUT
    if (tid < 52) lut16[tid] = (unsigned short)(256 * (tid / 7) + 16 * (tid % 7));

    // ---- zero input halo
    if (tid < 232) {
        int im = tid / 116;
        int r  = tid - im * 116;
        int idx;
        if      (r < 30) idx = r;
        else if (r < 60) idx = 29 * 30 + (r - 30);
        else if (r < 88) idx = (r - 60 + 1) * 30;
        else             idx = (r - 88 + 1) * 30 + 29;
        sx[im][idx] = 0.f;
    }
    // ---- stage interior via float4 (392 tasks)
    {
        const float4* xb4 = (const float4*)(x + (size_t)img0 * 784);
        for (int i = tid; i < 392; i += 256) {
            int im  = i / 196;
            int j   = i - im * 196;
            int row = j / 7;
            int c4  = j - row * 7;
            float4 f = xb4[i];
            float* dp = &sx[im][(row + 1) * 30 + c4 * 4 + 1];
            dp[0] = f.x; dp[1] = f.y; dp[2] = f.z; dp[3] = f.w;
        }
    }
    // ---- zero s1t halo
    for (int q = tid; q < 120; q += 256) {
        int im = q / 60, r = q - im * 60;
        int Y, X;
        if      (r < 16) { Y = 0;          X = r; }
        else if (r < 32) { Y = 15;         X = r - 16; }
        else if (r < 46) { Y = r - 32 + 1; X = 0; }
        else             { Y = r - 46 + 1; X = 15; }
        *(uint4*)&s1t[im][Y][X][0] = make_uint4(0, 0, 0, 0);
    }
    // ---- zero s1f
    for (int q = tid; q < 192; q += 256) ((float4*)s1f)[q] = make_float4(0, 0, 0, 0);
    __syncthreads();

    // ---- conv1 (1->8) + relu + pool via v_pk_fma_f32: 196 tasks = (img,py,pxq)
    if (tid < 196) {
        int im  = tid / 98;
        int r   = tid - im * 98;
        int py  = r / 7;
        int pxq = r - py * 7;
        const float* sp = &sx[im][(2 * py) * 30 + 4 * pxq];  // 8B-aligned base
        f32x2 rp[4][3], sh[4][2];
        #pragma unroll
        for (int wy = 0; wy < 4; ++wy) {
            rp[wy][0] = *(const f32x2*)(sp + wy * 30);
            rp[wy][1] = *(const f32x2*)(sp + wy * 30 + 2);
            rp[wy][2] = *(const f32x2*)(sp + wy * 30 + 4);
            sh[wy][0] = (f32x2){rp[wy][0].y, rp[wy][1].x};   // (w1,w2)
            sh[wy][1] = (f32x2){rp[wy][1].y, rp[wy][2].x};   // (w3,w4)
        }
        float va[8], vb[8];
        const bool sf = (py <= 2) && (pxq <= 4);
        #pragma unroll
        for (int c = 0; c < 8; ++c) {
            const float* wp = &c1w[c * 9];            // uniform -> s_load
            float bb = c1b[c];
            f32x2 A[2][2];                             // [q][dy], lanes = dx
            A[0][0] = (f32x2){bb, bb}; A[0][1] = (f32x2){bb, bb};
            A[1][0] = (f32x2){bb, bb}; A[1][1] = (f32x2){bb, bb};
            #pragma unroll
            for (int ky = 0; ky < 3; ++ky) {
                #pragma unroll
                for (int kx = 0; kx < 3; ++kx) {
                    float wv = wp[ky * 3 + kx];
                    f32x2 wv2 = (f32x2){wv, wv};
                    #pragma unroll
                    for (int dy = 0; dy < 2; ++dy) {
                        int row = dy + ky;
                        f32x2 s0 = (kx == 0) ? rp[row][0] : (kx == 1) ? sh[row][0] : rp[row][1];
                        f32x2 s1v = (kx == 0) ? rp[row][1] : (kx == 1) ? sh[row][1] : rp[row][2];
                        A[0][dy] = __builtin_elementwise_fma(s0,  wv2, A[0][dy]);
                        A[1][dy] = __builtin_elementwise_fma(s1v, wv2, A[1][dy]);
                    }
                }
            }
            f32x2 m0 = __builtin_elementwise_max(A[0][0], A[0][1]);
            f32x2 m1 = __builtin_elementwise_max(A[1][0], A[1][1]);
            va[c] = fmaxf(fmaxf(m0.x, m0.y), 0.f);
            vb[c] = fmaxf(fmaxf(m1.x, m1.y), 0.f);
            if (sf) {
                s1f[im][py + 1][2 * pxq + 1][c] = va[c];
                s1f[im][py + 1][2 * pxq + 2][c] = vb[c];
            }
        }
        uint4 pka, pkb;
        pka.x = cvtpk_bf16(va[0], va[1]); pka.y = cvtpk_bf16(va[2], va[3]);
        pka.z = cvtpk_bf16(va[4], va[5]); pka.w = cvtpk_bf16(va[6], va[7]);
        pkb.x = cvtpk_bf16(vb[0], vb[1]); pkb.y = cvtpk_bf16(vb[2], vb[3]);
        pkb.z = cvtpk_bf16(vb[4], vb[5]); pkb.w = cvtpk_bf16(vb[6], vb[7]);
        *(uint4*)&s1t[im][py + 1][2 * pxq + 1][0] = pka;
        *(uint4*)&s1t[im][py + 1][2 * pxq + 2][0] = pkb;
    }
    __syncthreads();

    // ---- conv2 (8->16) + relu + pool via MFMA, LUT-addressed quad-major M
    {
        const int wv   = __builtin_amdgcn_readfirstlane(tid >> 6);
        const int im   = wv >> 1;
        const int half = wv & 1;
        const int l    = tid & 63;
        const int grp  = l >> 4;
        const int m15  = l & 15;

        // ---- B-fragments gathered directly from c2w (L2-hot, 4.6 KB)
        //   bfr[g][j] = c2w[(m15*8 + j)*9 + kp], kp = 4g+grp (0 if kp>8)
        union { uint4 u; bf16x8 v; } bfr[3];
        {
            const float* wbase = c2w + (size_t)m15 * 72;
            #pragma unroll
            for (int g = 0; g < 2; ++g) {             // kp = grp / 4+grp, always <9
                int kp = 4 * g + grp;
                #pragma unroll
                for (int jj = 0; jj < 4; ++jj) {
                    float a = wbase[(2 * jj) * 9 + kp];
                    float b = wbase[(2 * jj + 1) * 9 + kp];
                    ((unsigned*)&bfr[g].u)[jj] = cvtpk_bf16(a, b);
                }
            }
            {                                          // g=2: kp = 8+grp, valid only grp==0
                int kp = (grp == 0) ? 8 : 0;           // clamp to in-bounds
                #pragma unroll
                for (int jj = 0; jj < 4; ++jj) {
                    float a = wbase[(2 * jj) * 9 + kp];
                    float b = wbase[(2 * jj + 1) * 9 + kp];
                    unsigned pk = cvtpk_bf16(a, b);
                    ((unsigned*)&bfr[2].u)[jj] = (grp == 0) ? pk : 0u;
                }
            }
        }

        int koff[3];
        #pragma unroll
        for (int g = 0; g < 3; ++g) {
            int kp = 4 * g + grp;
            koff[g] = (kp < 9) ? ((kp / 3) * 16 + (kp % 3)) * 8 : 0;
        }
        const float bias = c2b[m15];
        unsigned short* s2b = (unsigned short*)&sx[im][0];   // input dead -> bf16 flat

        const int n   = 7 - half;                 // 7 iters for half=0, 6 for half=1
        const int qa0 = 4 * half + (m15 >> 2);
        const int sub = ((m15 & 2) >> 1) * 128 + (m15 & 1) * 8;
        const unsigned short* s1b = &s1t[im][0][0][0];

        unsigned roff[7];
        #pragma unroll
        for (int i = 0; i < 7; ++i) {
            if (i < n) {
                int qa = qa0 + 8 * i;
                if (qa > 48) qa = 48;             // replicate row 48 for pad lanes
                roff[i] = lut16[qa];
            }
        }

        int qo = 4 * half + grp;                  // output quad, +8 per iter
        #pragma unroll
        for (int i = 0; i < 7; ++i) {
            if (i < n) {
                const unsigned short* ab = s1b + roff[i] + sub;
                f32x4 acc = {};
                #pragma unroll
                for (int g = 0; g < 3; ++g) {
                    bf16x8 a = *(const bf16x8*)(ab + koff[g]);
                    acc = __builtin_amdgcn_mfma_f32_16x16x32_bf16(a, bfr[g].v, acc, 0, 0, 0);
                }
                float m = fmaxf(fmaxf(acc[0], acc[1]), fmaxf(acc[2], acc[3]));
                float val = fmaxf(m + bias, 0.f);
                if (qo < 49) s2b[m15 * 49 + qo] = (unsigned short)cvtpk_bf16(val, val);
                qo += 8;
            }
        }

        // ---- exact fp32 flat[:4] (ch 0, quads 0..3) on waves 1,3 lanes 0..15
        if (half == 1 && l < 16) {
            int q  = l >> 2;
            int dy = (l >> 1) & 1, dx = l & 1;
            float a = 0.f;
            #pragma unroll
            for (int kp = 0; kp < 9; ++kp) {
                int ky = kp / 3, kx = kp - 3 * ky;
                const float* spf = &s1f[im][dy + ky][2 * q + dx + kx][0];
                #pragma unroll
                for (int ic = 0; ic < 8; ++ic)
                    a += spf[ic] * c2w[ic * 9 + kp];   // uniform -> s_load
            }
            float m1 = fmaxf(a, __shfl_xor(a, 1));
            float m2 = fmaxf(m1, __shfl_xor(m1, 2));
            if ((l & 3) == 0)
                exact4g[(size_t)(img0 + im) * 4 + q] = fmaxf(m2 + c2b[0], 0.f);
        }
    }
    __syncthreads();

    // ---- flat copy LDS(bf16) -> global via uint4: 100 x 16B per image
    if (tid < 200) {
        int im = tid / 100;
        int j  = tid - im * 100;
        const uint4* s2v = (const uint4*)&sx[im][0];
        uint4 v = (j < 98) ? s2v[j] : make_uint4(0, 0, 0, 0);
        *(uint4*)(flatb + (size_t)(img0 + im) * 800 + j * 8) = v;
    }
}

// ---------------------------------------------------------------------------
// Kernel 2: fc1 (MFMA bf16) + relu + fc2 fused -> fct[4][bsz] + BN partials
// ---------------------------------------------------------------------------
__global__ __launch_bounds__(128) void k_fc(
    const unsigned short* __restrict__ flatb, const unsigned short* __restrict__ Bp,
    const float* __restrict__ fc1b, const float* __restrict__ fc2w,
    const float* __restrict__ fc2b, float* __restrict__ fct,
    float* __restrict__ partial, int bsz)
{
    __shared__ float h[2][16][68];
    __shared__ float ps[2][4][2];

    const int tid  = threadIdx.x;
    const int w    = __builtin_amdgcn_readfirstlane(tid >> 6);
    const int l    = tid & 63;
    const int img0 = blockIdx.x * 32 + w * 16;
    const int m15  = l & 15;
    const int grp  = l >> 4;

    const unsigned short* aptr = flatb + (size_t)(img0 + m15) * 800 + grp * 8;
    const unsigned short* bptr = Bp + (size_t)l * 8;

    f32x4 acc[4] = {};
    for (int kb = 0; kb < 25; ++kb) {
        bf16x8 a = *(const bf16x8*)(aptr + kb * 32);
        #pragma unroll
        for (int nf = 0; nf < 4; ++nf) {
            bf16x8 b = *(const bf16x8*)(bptr + (size_t)(kb * 4 + nf) * 64 * 8);
            acc[nf] = __builtin_amdgcn_mfma_f32_16x16x32_bf16(a, b, acc[nf], 0, 0, 0);
        }
    }

    #pragma unroll
    for (int nf = 0; nf < 4; ++nf) {
        int j = nf * 16 + m15;
        float bj = fc1b[j];
        #pragma unroll
        for (int r = 0; r < 4; ++r)
            h[w][grp * 4 + r][j] = fmaxf(acc[nf][r] + bj, 0.f);
    }
    __syncthreads();

    {
        int im = m15, ch = grp;
        float a = fc2b[ch];
        const float* hp = &h[w][im][0];
        const float* wp = &fc2w[ch * 64];
        #pragma unroll 8
        for (int o = 0; o < 64; ++o) a += hp[o] * wp[o];
        fct[(size_t)ch * bsz + img0 + im] = a;

        float s = a, ss = a * a;
        #pragma unroll
        for (int off = 1; off < 16; off <<= 1) {
            s  += __shfl_xor(s,  off);
            ss += __shfl_xor(ss, off);
        }
        if (m15 == 0) { ps[w][ch][0] = s; ps[w][ch][1] = ss; }
    }
    __syncthreads();

    if (tid < 8) {
        int c = tid & 3, st = tid >> 2;
        partial[(size_t)blockIdx.x * 8 + st * 4 + c] =
            ps[0][c][st] + ps[1][c][st];
    }
}

// ---------------------------------------------------------------------------
// Kernel 3: BN finalize + heads + BN apply — 32 blocks
// ---------------------------------------------------------------------------
__global__ __launch_bounds__(256) void k_bnheads(
    const float* __restrict__ partial, const float* __restrict__ g,
    const float* __restrict__ bb, const float* __restrict__ fct,
    const float* __restrict__ exact4g,
    const float* __restrict__ sw1, const float* __restrict__ sb1,
    const float* __restrict__ sw2, const float* __restrict__ sb2,
    const float* __restrict__ ew1, const float* __restrict__ eb1,
    const float* __restrict__ ew2, const float* __restrict__ eb2,
    const float* __restrict__ ew3, const float* __restrict__ eb3,
    const float* __restrict__ mem,
    float* __restrict__ out, int bsz)
{
    __shared__ float red[32][8];
    __shared__ float tot[8];
    __shared__ float sc[4], shf[4];

    const int tid = threadIdx.x;

    {
        int v = tid & 7, chunk = tid >> 3;
        float s = 0.f;
        #pragma unroll
        for (int i = 0; i < 8; ++i)
            s += partial[(size_t)(chunk * 8 + i) * 8 + v];
        red[chunk][v] = s;
    }
    __syncthreads();
    if (tid < 8) {
        float s = 0.f;
        #pragma unroll 8
        for (int c = 0; c < 32; ++c) s += red[c][tid];
        tot[tid] = s;
    }
    __syncthreads();
    if (tid < 4) {
        float n = (float)bsz;
        float mu  = tot[tid] / n;
        float var = tot[4 + tid] / n - mu * mu;
        float scale = g[tid] * rsqrtf(var + EPS_BN);
        sc[tid]  = scale;
        shf[tid] = bb[tid] - mu * scale;
    }
    __syncthreads();

    const int img = blockIdx.x * 256 + tid;
    const int off_samp = bsz * 4;
    const int off_reg  = bsz * 6;
    const int off_ker  = bsz * 7;

    {
        const float4 f = *(const float4*)(exact4g + (size_t)img * 4);
        const float f0 = f.x, f1 = f.y, f2 = f.z, f3 = f.w;
        float qq = f0 * f0 + f1 * f1 + f2 * f2 + f3 * f3;
        #pragma unroll
        for (int j = 0; j < 10; ++j) {
            float m0 = mem[j * 4 + 0], m1 = mem[j * 4 + 1];
            float m2 = mem[j * 4 + 2], m3 = mem[j * 4 + 3];
            float sq = qq + m0 * m0 + m1 * m1 + m2 * m2 + m3 * m3
                     - 2.f * (f0 * m0 + f1 * m1 + f2 * m2 + f3 * m3);
            out[off_ker + (size_t)img * 10 + j] = expf(-sq);
        }
        {
            float t1[4];
            #pragma unroll
            for (int j = 0; j < 4; ++j)
                t1[j] = tanhf(f0 * sw1[j * 2] + f1 * sw1[j * 2 + 1] + sb1[j]);
            float s0 = sb2[0], s1v = sb2[1];
            #pragma unroll
            for (int j = 0; j < 4; ++j) { s0 += t1[j] * sw2[j]; s1v += t1[j] * sw2[4 + j]; }
            float mx = fmaxf(s0, s1v);
            float e0 = expf(s0 - mx), e1 = expf(s1v - mx);
            float inv = 1.f / (e0 + e1);
            out[off_samp + (size_t)img * 2 + 0] = e0 * inv;
            out[off_samp + (size_t)img * 2 + 1] = e1 * inv;
        }
        {
            float e1a[8];
            #pragma unroll
            for (int j = 0; j < 8; ++j)
                e1a[j] = tanhf(f0 * ew1[j * 2] + f1 * ew1[j * 2 + 1] + eb1[j]);
            float rg = eb3[0];
            #pragma unroll
            for (int m = 0; m < 4; ++m) {
                float a = eb2[m];
                #pragma unroll
                for (int j = 0; j < 8; ++j) a += e1a[j] * ew2[m * 8 + j];
                rg += tanhf(a) * ew3[m];
            }
            out[off_reg + img] = rg;
        }
    }

    {
        float4 r;
        r.x = fct[img]           * sc[0] + shf[0];
        r.y = fct[bsz + img]     * sc[1] + shf[1];
        r.z = fct[2 * bsz + img] * sc[2] + shf[2];
        r.w = fct[3 * bsz + img] * sc[3] + shf[3];
        *(float4*)(out + (size_t)img * 4) = r;
    }
}

// ---------------------------------------------------------------------------
extern "C" void kernel_launch(void* const* d_in, const int* in_sizes, int n_in,
                              void* d_out, int out_size, void* d_ws, size_t ws_size,
                              hipStream_t stream) {
    const float* x     = (const float*)d_in[0];
    const float* c1w   = (const float*)d_in[1];
    const float* c1b   = (const float*)d_in[2];
    const float* c2w   = (const float*)d_in[3];
    const float* c2b   = (const float*)d_in[4];
    const float* fc1w  = (const float*)d_in[5];
    const float* fc1b  = (const float*)d_in[6];
    const float* fc2w  = (const float*)d_in[7];
    const float* fc2b  = (const float*)d_in[8];
    const float* bng   = (const float*)d_in[9];
    const float* bnb   = (const float*)d_in[10];
    const float* sw1   = (const float*)d_in[11];
    const float* sb1   = (const float*)d_in[12];
    const float* sw2   = (const float*)d_in[13];
    const float* sb2   = (const float*)d_in[14];
    const float* ew1   = (const float*)d_in[15];
    const float* eb1   = (const float*)d_in[16];
    const float* ew2   = (const float*)d_in[17];
    const float* eb2   = (const float*)d_in[18];
    const float* ew3   = (const float*)d_in[19];
    const float* eb3   = (const float*)d_in[20];
    const float* mem   = (const float*)d_in[21];

    const int bsz = in_sizes[0] / 784;         // 8192
    float* out = (float*)d_out;

    unsigned short* flatb = (unsigned short*)d_ws;           // bsz*800 bf16
    unsigned short* Bp    = flatb + (size_t)bsz * 800;       // 51200 bf16
    float* fct            = (float*)(Bp + 51200);            // 4*bsz
    float* partial        = fct + (size_t)bsz * 4;           // 256*8
    float* exact4g        = partial + 2048;                  // 4*bsz

    k_conv<<<bsz / 2, 256, 0, stream>>>(x, c1w, c1b, c2w, c2b,
                                        fc1w, Bp, flatb, exact4g, bsz);
    k_fc<<<bsz / 32, 128, 0, stream>>>(flatb, Bp, fc1b, fc2w, fc2b,
                                       fct, partial, bsz);
    k_bnheads<<<bsz / 256, 256, 0, stream>>>(partial, bng, bnb, fct, exact4g,
                                             sw1, sb1, sw2, sb2,
                                             ew1, eb1, ew2, eb2, ew3, eb3, mem,
                                             out, bsz);
}

// Round 14
// 44.761 us; speedup vs baseline: 1.7330x; 1.7330x over previous
//
#include <hip/hip_runtime.h>
#include <math.h>

#define EPS_BN 1e-5f

typedef float  f32x4  __attribute__((ext_vector_type(4)));
typedef float  f32x2  __attribute__((ext_vector_type(2)));
typedef short  bf16x8 __attribute__((ext_vector_type(8)));

__device__ inline unsigned short f2bf(float f) {
    union { float f; unsigned u; } c; c.f = f;
    unsigned u = c.u;
    return (unsigned short)((u + 0x7FFFu + ((u >> 16) & 1u)) >> 16);  // RNE
}
// v_cvt_pk_bf16_f32: lo=cvt(a), hi=cvt(b), RNE — bit-identical to f2bf pair
__device__ inline unsigned cvtpk_bf16(float a, float b) {
    unsigned r;
    asm("v_cvt_pk_bf16_f32 %0, %1, %2" : "=v"(r) : "v"(a), "v"(b));
    return r;
}

// ---------------------------------------------------------------------------
// Kernel 1: conv1(pk_fma) + conv2(MFMA, LUT-addressed) + bf16 flat + exact4
//   2 img/block; blocks 0..199 also pack fc1_w -> Bp (MFMA B-frag).
// ---------------------------------------------------------------------------
__global__ __launch_bounds__(256, 8) void k_conv(
    const float* __restrict__ x,
    const float* __restrict__ c1w, const float* __restrict__ c1b,
    const float* __restrict__ c2w, const float* __restrict__ c2b,
    const float* __restrict__ fc1w, unsigned short* __restrict__ Bp,
    unsigned short* __restrict__ flatb, float* __restrict__ exact4g, int bsz)
{
    __shared__ float sx[2][900];                          // 30x30 halo input; later flat(bf16)
    __shared__ __align__(16) unsigned short s1t[2][16][16][8]; // bf16 conv1 out, halo
    __shared__ float s1f[2][4][12][8];                    // f32 corner for exact heads
    __shared__ __align__(16) unsigned short sBc2[1536];   // conv2 B-fragments
    __shared__ unsigned short lut16[56];                  // qa -> elem offset in s1t

    const int tid  = threadIdx.x;
    const int img0 = blockIdx.x * 2;

    // ---- blocks 0..199 pack Bp (fc1 weights)
    if (blockIdx.x < 200) {
        int t = blockIdx.x * 256 + tid;        // < 51200
        int j  = t & 7;
        int l  = (t >> 3) & 63;
        int nf = (t >> 9) & 3;
        int kb = t >> 11;
        int k  = kb * 32 + (l >> 4) * 8 + j;
        int o  = nf * 16 + (l & 15);
        float v = (k < 784) ? fc1w[o * 784 + k] : 0.f;
        Bp[t] = f2bf(v);
    }

    // ---- pack conv2 weights into LDS fragments
    for (int t = tid; t < 1536; t += 256) {
        int j  = t & 7;            // ic
        int l  = (t >> 3) & 63;
        int g  = t >> 9;           // k-group
        int kp = 4 * g + (l >> 4); // kernel position
        int oc = l & 15;
        float v = (kp < 9) ? c2w[(oc * 8 + j) * 9 + kp] : 0.f;
        sBc2[t] = f2bf(v);
    }

    // ---- conv2 address LUT: quad qa -> element offset (row-pair, col-pair)
    if (tid < 52) lut16[tid] = (unsigned short)(256 * (tid / 7) + 16 * (tid % 7));

    // ---- zero input halo
    if (tid < 232) {
        int im = tid / 116;
        int r  = tid - im * 116;
        int idx;
        if      (r < 30) idx = r;
        else if (r < 60) idx = 29 * 30 + (r - 30);
        else if (r < 88) idx = (r - 60 + 1) * 30;
        else             idx = (r - 88 + 1) * 30 + 29;
        sx[im][idx] = 0.f;
    }
    // ---- stage interior via float4 (392 tasks)
    {
        const float4* xb4 = (const float4*)(x + (size_t)img0 * 784);
        for (int i = tid; i < 392; i += 256) {
            int im  = i / 196;
            int j   = i - im * 196;          // float4 index in image
            int row = j / 7;
            int c4  = j - row * 7;
            float4 f = xb4[i];
            float* dp = &sx[im][(row + 1) * 30 + c4 * 4 + 1];
            dp[0] = f.x; dp[1] = f.y; dp[2] = f.z; dp[3] = f.w;
        }
    }
    // ---- zero s1t halo
    for (int q = tid; q < 120; q += 256) {
        int im = q / 60, r = q - im * 60;
        int Y, X;
        if      (r < 16) { Y = 0;          X = r; }
        else if (r < 32) { Y = 15;         X = r - 16; }
        else if (r < 46) { Y = r - 32 + 1; X = 0; }
        else             { Y = r - 46 + 1; X = 15; }
        *(uint4*)&s1t[im][Y][X][0] = make_uint4(0, 0, 0, 0);
    }
    // ---- zero s1f
    for (int q = tid; q < 192; q += 256) ((float4*)s1f)[q] = make_float4(0, 0, 0, 0);
    __syncthreads();

    // ---- conv1 (1->8) + relu + pool via v_pk_fma_f32: 196 tasks = (img,py,pxq)
    if (tid < 196) {
        int im  = tid / 98;
        int r   = tid - im * 98;
        int py  = r / 7;
        int pxq = r - py * 7;
        const float* sp = &sx[im][(2 * py) * 30 + 4 * pxq];  // 8B-aligned base
        f32x2 rp[4][3], sh[4][2];
        #pragma unroll
        for (int wy = 0; wy < 4; ++wy) {
            rp[wy][0] = *(const f32x2*)(sp + wy * 30);
            rp[wy][1] = *(const f32x2*)(sp + wy * 30 + 2);
            rp[wy][2] = *(const f32x2*)(sp + wy * 30 + 4);
            sh[wy][0] = (f32x2){rp[wy][0].y, rp[wy][1].x};   // (w1,w2)
            sh[wy][1] = (f32x2){rp[wy][1].y, rp[wy][2].x};   // (w3,w4)
        }
        float va[8], vb[8];
        const bool sf = (py <= 2) && (pxq <= 4);
        #pragma unroll
        for (int c = 0; c < 8; ++c) {
            const float* wp = &c1w[c * 9];            // uniform -> s_load
            float bb = c1b[c];
            f32x2 A[2][2];                             // [q][dy], lanes = dx
            A[0][0] = (f32x2){bb, bb}; A[0][1] = (f32x2){bb, bb};
            A[1][0] = (f32x2){bb, bb}; A[1][1] = (f32x2){bb, bb};
            #pragma unroll
            for (int ky = 0; ky < 3; ++ky) {
                #pragma unroll
                for (int kx = 0; kx < 3; ++kx) {
                    float wv = wp[ky * 3 + kx];
                    f32x2 wv2 = (f32x2){wv, wv};
                    #pragma unroll
                    for (int dy = 0; dy < 2; ++dy) {
                        int row = dy + ky;
                        f32x2 s0 = (kx == 0) ? rp[row][0] : (kx == 1) ? sh[row][0] : rp[row][1];
                        f32x2 s1v = (kx == 0) ? rp[row][1] : (kx == 1) ? sh[row][1] : rp[row][2];
                        A[0][dy] = __builtin_elementwise_fma(s0,  wv2, A[0][dy]);
                        A[1][dy] = __builtin_elementwise_fma(s1v, wv2, A[1][dy]);
                    }
                }
            }
            f32x2 m0 = __builtin_elementwise_max(A[0][0], A[0][1]);
            f32x2 m1 = __builtin_elementwise_max(A[1][0], A[1][1]);
            va[c] = fmaxf(fmaxf(m0.x, m0.y), 0.f);
            vb[c] = fmaxf(fmaxf(m1.x, m1.y), 0.f);
            if (sf) {
                s1f[im][py + 1][2 * pxq + 1][c] = va[c];
                s1f[im][py + 1][2 * pxq + 2][c] = vb[c];
            }
        }
        uint4 pka, pkb;
        pka.x = cvtpk_bf16(va[0], va[1]); pka.y = cvtpk_bf16(va[2], va[3]);
        pka.z = cvtpk_bf16(va[4], va[5]); pka.w = cvtpk_bf16(va[6], va[7]);
        pkb.x = cvtpk_bf16(vb[0], vb[1]); pkb.y = cvtpk_bf16(vb[2], vb[3]);
        pkb.z = cvtpk_bf16(vb[4], vb[5]); pkb.w = cvtpk_bf16(vb[6], vb[7]);
        *(uint4*)&s1t[im][py + 1][2 * pxq + 1][0] = pka;
        *(uint4*)&s1t[im][py + 1][2 * pxq + 2][0] = pkb;
    }
    __syncthreads();

    // ---- conv2 (8->16) + relu + pool via MFMA, LUT-addressed quad-major M
    {
        const int wv   = __builtin_amdgcn_readfirstlane(tid >> 6);
        const int im   = wv >> 1;
        const int half = wv & 1;
        const int l    = tid & 63;
        const int grp  = l >> 4;
        const int m15  = l & 15;

        bf16x8 bfr[3];
        #pragma unroll
        for (int g = 0; g < 3; ++g)
            bfr[g] = *(const bf16x8*)(sBc2 + (size_t)(g * 64 + l) * 8);

        int koff[3];
        #pragma unroll
        for (int g = 0; g < 3; ++g) {
            int kp = 4 * g + grp;
            koff[g] = (kp < 9) ? ((kp / 3) * 16 + (kp % 3)) * 8 : 0;
        }
        const float bias = c2b[m15];
        unsigned short* s2b = (unsigned short*)&sx[im][0];   // input dead -> bf16 flat

        const int n   = 7 - half;                 // 7 iters for half=0, 6 for half=1
        const int qa0 = 4 * half + (m15 >> 2);
        const int sub = ((m15 & 2) >> 1) * 128 + (m15 & 1) * 8;
        const unsigned short* s1b = &s1t[im][0][0][0];

        unsigned roff[7];
        #pragma unroll
        for (int i = 0; i < 7; ++i) {
            if (i < n) {
                int qa = qa0 + 8 * i;
                if (qa > 48) qa = 48;             // replicate row 48 for pad lanes
                roff[i] = lut16[qa];
            }
        }

        int qo = 4 * half + grp;                  // output quad, +8 per iter
        #pragma unroll
        for (int i = 0; i < 7; ++i) {
            if (i < n) {
                const unsigned short* ab = s1b + roff[i] + sub;
                f32x4 acc = {};
                #pragma unroll
                for (int g = 0; g < 3; ++g) {
                    bf16x8 a = *(const bf16x8*)(ab + koff[g]);
                    acc = __builtin_amdgcn_mfma_f32_16x16x32_bf16(a, bfr[g], acc, 0, 0, 0);
                }
                float m = fmaxf(fmaxf(acc[0], acc[1]), fmaxf(acc[2], acc[3]));
                float val = fmaxf(m + bias, 0.f);
                if (qo < 49) s2b[m15 * 49 + qo] = (unsigned short)cvtpk_bf16(val, val);
                qo += 8;
            }
        }

        // ---- exact fp32 flat[:4] (ch 0, quads 0..3) on waves 1,3 lanes 0..15
        if (half == 1 && l < 16) {
            int q  = l >> 2;
            int dy = (l >> 1) & 1, dx = l & 1;
            float a = 0.f;
            #pragma unroll
            for (int kp = 0; kp < 9; ++kp) {
                int ky = kp / 3, kx = kp - 3 * ky;
                const float* spf = &s1f[im][dy + ky][2 * q + dx + kx][0];
                #pragma unroll
                for (int ic = 0; ic < 8; ++ic)
                    a += spf[ic] * c2w[ic * 9 + kp];   // uniform -> s_load
            }
            float m1 = fmaxf(a, __shfl_xor(a, 1));
            float m2 = fmaxf(m1, __shfl_xor(m1, 2));
            if ((l & 3) == 0)
                exact4g[(size_t)(img0 + im) * 4 + q] = fmaxf(m2 + c2b[0], 0.f);
        }
    }
    __syncthreads();

    // ---- flat copy LDS(bf16) -> global via uint4: 100 x 16B per image
    if (tid < 200) {
        int im = tid / 100;
        int j  = tid - im * 100;                  // uint4 index within row
        const uint4* s2v = (const uint4*)&sx[im][0];
        uint4 v = (j < 98) ? s2v[j] : make_uint4(0, 0, 0, 0);
        *(uint4*)(flatb + (size_t)(img0 + im) * 800 + j * 8) = v;
    }
}

// ---------------------------------------------------------------------------
// Kernel 2: fc1 (MFMA bf16) + relu + fc2 fused -> fct[4][bsz] + BN partials
// ---------------------------------------------------------------------------
__global__ __launch_bounds__(128) void k_fc(
    const unsigned short* __restrict__ flatb, const unsigned short* __restrict__ Bp,
    const float* __restrict__ fc1b, const float* __restrict__ fc2w,
    const float* __restrict__ fc2b, float* __restrict__ fct,
    float* __restrict__ partial, int bsz)
{
    __shared__ float h[2][16][68];
    __shared__ float ps[2][4][2];

    const int tid  = threadIdx.x;
    const int w    = __builtin_amdgcn_readfirstlane(tid >> 6);
    const int l    = tid & 63;
    const int img0 = blockIdx.x * 32 + w * 16;
    const int m15  = l & 15;
    const int grp  = l >> 4;

    const unsigned short* aptr = flatb + (size_t)(img0 + m15) * 800 + grp * 8;
    const unsigned short* bptr = Bp + (size_t)l * 8;

    f32x4 acc[4] = {};
    for (int kb = 0; kb < 25; ++kb) {
        bf16x8 a = *(const bf16x8*)(aptr + kb * 32);
        #pragma unroll
        for (int nf = 0; nf < 4; ++nf) {
            bf16x8 b = *(const bf16x8*)(bptr + (size_t)(kb * 4 + nf) * 64 * 8);
            acc[nf] = __builtin_amdgcn_mfma_f32_16x16x32_bf16(a, b, acc[nf], 0, 0, 0);
        }
    }

    #pragma unroll
    for (int nf = 0; nf < 4; ++nf) {
        int j = nf * 16 + m15;
        float bj = fc1b[j];
        #pragma unroll
        for (int r = 0; r < 4; ++r)
            h[w][grp * 4 + r][j] = fmaxf(acc[nf][r] + bj, 0.f);
    }
    __syncthreads();

    {
        int im = m15, ch = grp;
        float a = fc2b[ch];
        const float* hp = &h[w][im][0];
        const float* wp = &fc2w[ch * 64];
        #pragma unroll 8
        for (int o = 0; o < 64; ++o) a += hp[o] * wp[o];
        fct[(size_t)ch * bsz + img0 + im] = a;

        float s = a, ss = a * a;
        #pragma unroll
        for (int off = 1; off < 16; off <<= 1) {
            s  += __shfl_xor(s,  off);
            ss += __shfl_xor(ss, off);
        }
        if (m15 == 0) { ps[w][ch][0] = s; ps[w][ch][1] = ss; }
    }
    __syncthreads();

    if (tid < 8) {
        int c = tid & 3, st = tid >> 2;
        partial[(size_t)blockIdx.x * 8 + st * 4 + c] =
            ps[0][c][st] + ps[1][c][st];
    }
}

// ---------------------------------------------------------------------------
// Kernel 3: BN finalize + heads + BN apply — 32 blocks
// ---------------------------------------------------------------------------
__global__ __launch_bounds__(256) void k_bnheads(
    const float* __restrict__ partial, const float* __restrict__ g,
    const float* __restrict__ bb, const float* __restrict__ fct,
    const float* __restrict__ exact4g,
    const float* __restrict__ sw1, const float* __restrict__ sb1,
    const float* __restrict__ sw2, const float* __restrict__ sb2,
    const float* __restrict__ ew1, const float* __restrict__ eb1,
    const float* __restrict__ ew2, const float* __restrict__ eb2,
    const float* __restrict__ ew3, const float* __restrict__ eb3,
    const float* __restrict__ mem,
    float* __restrict__ out, int bsz)
{
    __shared__ float red[32][8];
    __shared__ float tot[8];
    __shared__ float sc[4], shf[4];

    const int tid = threadIdx.x;

    {
        int v = tid & 7, chunk = tid >> 3;
        float s = 0.f;
        #pragma unroll
        for (int i = 0; i < 8; ++i)
            s += partial[(size_t)(chunk * 8 + i) * 8 + v];
        red[chunk][v] = s;
    }
    __syncthreads();
    if (tid < 8) {
        float s = 0.f;
        #pragma unroll 8
        for (int c = 0; c < 32; ++c) s += red[c][tid];
        tot[tid] = s;
    }
    __syncthreads();
    if (tid < 4) {
        float n = (float)bsz;
        float mu  = tot[tid] / n;
        float var = tot[4 + tid] / n - mu * mu;
        float scale = g[tid] * rsqrtf(var + EPS_BN);
        sc[tid]  = scale;
        shf[tid] = bb[tid] - mu * scale;
    }
    __syncthreads();

    const int img = blockIdx.x * 256 + tid;
    const int off_samp = bsz * 4;
    const int off_reg  = bsz * 6;
    const int off_ker  = bsz * 7;

    {
        const float4 f = *(const float4*)(exact4g + (size_t)img * 4);
        const float f0 = f.x, f1 = f.y, f2 = f.z, f3 = f.w;
        float qq = f0 * f0 + f1 * f1 + f2 * f2 + f3 * f3;
        #pragma unroll
        for (int j = 0; j < 10; ++j) {
            float m0 = mem[j * 4 + 0], m1 = mem[j * 4 + 1];
            float m2 = mem[j * 4 + 2], m3 = mem[j * 4 + 3];
            float sq = qq + m0 * m0 + m1 * m1 + m2 * m2 + m3 * m3
                     - 2.f * (f0 * m0 + f1 * m1 + f2 * m2 + f3 * m3);
            out[off_ker + (size_t)img * 10 + j] = expf(-sq);
        }
        {
            float t1[4];
            #pragma unroll
            for (int j = 0; j < 4; ++j)
                t1[j] = tanhf(f0 * sw1[j * 2] + f1 * sw1[j * 2 + 1] + sb1[j]);
            float s0 = sb2[0], s1v = sb2[1];
            #pragma unroll
            for (int j = 0; j < 4; ++j) { s0 += t1[j] * sw2[j]; s1v += t1[j] * sw2[4 + j]; }
            float mx = fmaxf(s0, s1v);
            float e0 = expf(s0 - mx), e1 = expf(s1v - mx);
            float inv = 1.f / (e0 + e1);
            out[off_samp + (size_t)img * 2 + 0] = e0 * inv;
            out[off_samp + (size_t)img * 2 + 1] = e1 * inv;
        }
        {
            float e1a[8];
            #pragma unroll
            for (int j = 0; j < 8; ++j)
                e1a[j] = tanhf(f0 * ew1[j * 2] + f1 * ew1[j * 2 + 1] + eb1[j]);
            float rg = eb3[0];
            #pragma unroll
            for (int m = 0; m < 4; ++m) {
                float a = eb2[m];
                #pragma unroll
                for (int j = 0; j < 8; ++j) a += e1a[j] * ew2[m * 8 + j];
                rg += tanhf(a) * ew3[m];
            }
            out[off_reg + img] = rg;
        }
    }

    {
        float4 r;
        r.x = fct[img]           * sc[0] + shf[0];
        r.y = fct[bsz + img]     * sc[1] + shf[1];
        r.z = fct[2 * bsz + img] * sc[2] + shf[2];
        r.w = fct[3 * bsz + img] * sc[3] + shf[3];
        *(float4*)(out + (size_t)img * 4) = r;
    }
}

// ---------------------------------------------------------------------------
extern "C" void kernel_launch(void* const* d_in, const int* in_sizes, int n_in,
                              void* d_out, int out_size, void* d_ws, size_t ws_size,
                              hipStream_t stream) {
    const float* x     = (const float*)d_in[0];
    const float* c1w   = (const float*)d_in[1];
    const float* c1b   = (const float*)d_in[2];
    const float* c2w   = (const float*)d_in[3];
    const float* c2b   = (const float*)d_in[4];
    const float* fc1w  = (const float*)d_in[5];
    const float* fc1b  = (const float*)d_in[6];
    const float* fc2w  = (const float*)d_in[7];
    const float* fc2b  = (const float*)d_in[8];
    const float* bng   = (const float*)d_in[9];
    const float* bnb   = (const float*)d_in[10];
    const float* sw1   = (const float*)d_in[11];
    const float* sb1   = (const float*)d_in[12];
    const float* sw2   = (const float*)d_in[13];
    const float* sb2   = (const float*)d_in[14];
    const float* ew1   = (const float*)d_in[15];
    const float* eb1   = (const float*)d_in[16];
    const float* ew2   = (const float*)d_in[17];
    const float* eb2   = (const float*)d_in[18];
    const float* ew3   = (const float*)d_in[19];
    const float* eb3   = (const float*)d_in[20];
    const float* mem   = (const float*)d_in[21];

    const int bsz = in_sizes[0] / 784;         // 8192
    float* out = (float*)d_out;

    unsigned short* flatb = (unsigned short*)d_ws;           // bsz*800 bf16
    unsigned short* Bp    = flatb + (size_t)bsz * 800;       // 51200 bf16
    float* fct            = (float*)(Bp + 51200);            // 4*bsz
    float* partial        = fct + (size_t)bsz * 4;           // 256*8
    float* exact4g        = partial + 2048;                  // 4*bsz

    k_conv<<<bsz / 2, 256, 0, stream>>>(x, c1w, c1b, c2w, c2b,
                                        fc1w, Bp, flatb, exact4g, bsz);
    k_fc<<<bsz / 32, 128, 0, stream>>>(flatb, Bp, fc1b, fc2w, fc2b,
                                       fct, partial, bsz);
    k_bnheads<<<bsz / 256, 256, 0, stream>>>(partial, bng, bnb, fct, exact4g,
                                             sw1, sb1, sw2, sb2,
                                             ew1, eb1, ew2, eb2, ew3, eb3, mem,
                                             out, bsz);
}